// Round 5
// baseline (495.878 us; speedup 1.0000x reference)
//
#include <hip/hip_runtime.h>
#include <cstdint>
#include <cstddef>

// Problem constants (fixed by the reference)
#define HW    16384
#define CCH   256
#define WID   128
#define NB    8
#define NSEL  500
#define NPAD  512
#define CPG   16     // channels per gather block

// ---------- helpers ----------
__device__ __forceinline__ unsigned key_of(float f) {
  // monotone float->uint map (larger float -> larger uint); logits are finite
  unsigned u = __float_as_uint(f);
  return (u & 0x80000000u) ? ~u : (u | 0x80000000u);
}

// ---------- K1: saliency logits + full x_main -> out copy (single read pass) ----------
// unroll 8 (r4 lesson: unroll 32 REGRESSED 81->93 µs; kernel is LLC-service-bound,
// deeper unroll only lengthens dependence chains). Channel order strictly
// sequential so logits stay bit-identical (topk set must not flip).
__global__ __launch_bounds__(256) void score_copy_kernel(const float* __restrict__ x,
                                                         const float* __restrict__ w,
                                                         float* __restrict__ logits,
                                                         float* __restrict__ out) {
  __shared__ float ws[CCH];
  int tid = threadIdx.x;
  ws[tid] = w[tid];
  __syncthreads();
  int pix = blockIdx.x * 256 + tid;            // 0 .. B*HW-1
  int b = pix >> 14, p = pix & (HW - 1);
  const float* xp = x + ((size_t)b << 22) + p; // b*C*HW
  float* op = out + ((size_t)b << 22) + p;
  float acc = 0.f;
#pragma unroll 8
  for (int c = 0; c < CCH; c++) {
    float v = xp[(size_t)c * HW];
    acc += v * ws[c];
    __builtin_nontemporal_store(v, &op[(size_t)c * HW]);
  }
  logits[pix] = acc;
}

// ---------- K2: per-batch top-500, 1024 threads, keys in registers ----------
__global__ __launch_bounds__(1024) void topk_kernel(const float* __restrict__ logits,
                                                    int* __restrict__ idx_out) {
  int b = blockIdx.x, tid = threadIdx.x;
  int lane = tid & 63, wave = tid >> 6;
  const float* lg = logits + (size_t)b * HW;
  __shared__ unsigned histp[16 * 256];  // per-wave private histograms (16 KB)
  __shared__ unsigned wtot[4];
  __shared__ unsigned wsum[16];
  __shared__ unsigned bc_prefix;
  __shared__ int bc_want;
  __shared__ int cnt;

  // each thread owns 16 CONSECUTIVE indices [tid*16, tid*16+16) in registers
  unsigned kreg[16];
#pragma unroll
  for (int j = 0; j < 4; j++) {
    float4 v = *(const float4*)&lg[tid * 16 + j * 4];
    kreg[4 * j + 0] = key_of(v.x);
    kreg[4 * j + 1] = key_of(v.y);
    kreg[4 * j + 2] = key_of(v.z);
    kreg[4 * j + 3] = key_of(v.w);
  }

  unsigned prefix = 0;
  int want = NSEL;
  for (int shift = 24; shift >= 0; shift -= 8) {
#pragma unroll
    for (int q = 0; q < 4; q++) histp[tid + q * 1024] = 0;
    __syncthreads();
    unsigned* myhist = histp + wave * 256;
#pragma unroll
    for (int j = 0; j < 16; j++) {
      unsigned u = kreg[j];
      bool m = (shift == 24) || ((u >> (shift + 8)) == (prefix >> (shift + 8)));
      if (m) atomicAdd(&myhist[(u >> shift) & 255u], 1u);
    }
    __syncthreads();
    // combine 16 private hists for this thread's bin, then shfl suffix-scan
    unsigned h = 0;
    if (tid < 256) {
#pragma unroll
      for (int w2 = 0; w2 < 16; w2++) h += histp[w2 * 256 + tid];
    }
    unsigned v = h;
#pragma unroll
    for (int o = 1; o < 64; o <<= 1) {
      unsigned t = __shfl_down(v, o);
      if (lane < 64 - o) v += t;
    }
    if (tid < 256 && lane == 0) wtot[wave] = v;  // wave total = suffix at lane 0
    __syncthreads();
    if (tid < 256) {
      unsigned sfx = v;
      for (int w2 = wave + 1; w2 < 4; w2++) sfx += wtot[w2];
      unsigned above = sfx - h;  // count strictly above this bin
      if ((int)sfx >= want && (int)above < want) {  // exactly one tid
        bc_prefix = prefix | ((unsigned)tid << shift);
        bc_want = want - (int)above;
      }
    }
    __syncthreads();
    prefix = bc_prefix;
    want = bc_want;
  }
  unsigned thr = prefix;  // exact key of boundary element; take `want` ties by lowest index

  int local = 0;
#pragma unroll
  for (int j = 0; j < 16; j++) local += (kreg[j] == thr) ? 1 : 0;
  // wave-level inclusive prefix scan of `local` over tid order
  unsigned pv = (unsigned)local;
#pragma unroll
  for (int o = 1; o < 64; o <<= 1) {
    unsigned t = __shfl_up(pv, o);
    if (lane >= o) pv += t;
  }
  if (lane == 63) wsum[wave] = pv;  // wave total
  if (tid == 0) cnt = 0;
  __syncthreads();
  unsigned woff = 0;
  for (int w2 = 0; w2 < wave; w2++) woff += wsum[w2];
  int rank = (int)(woff + pv) - local;  // exclusive prefix over tid*16+j order
#pragma unroll
  for (int j = 0; j < 16; j++) {
    unsigned u = kreg[j];
    bool take = (u > thr);
    if (u == thr) { if (rank < want) take = true; rank++; }
    if (take) {
      int s = atomicAdd(&cnt, 1);
      idx_out[b * NPAD + s] = tid * 16 + j;
    }
  }
}

// ---------- shared patch-weight computation ----------
__device__ __forceinline__ void patch_weights(int p, int* xc, int* yc, float* wx, float* wy) {
  int iy = p >> 7, ix = p & (WID - 1);
#pragma unroll
  for (int d = 0; d < 7; d++) {
    int t = ix + d - 3;
    bool in = (t >= 0) && (t < WID);
    xc[d] = in ? t : (t < 0 ? 0 : WID - 1);
    wx[d] = in ? 1.f : 0.5f;
    t = iy + d - 3;
    in = (t >= 0) && (t < WID);
    yc[d] = in ? t : (t < 0 ? 0 : WID - 1);
    wy[d] = in ? 1.f : 0.5f;
  }
}

// ---------- K3: DMA double-buffered plane gather ----------
__global__ __launch_bounds__(512) void gather_dma_kernel(const float* __restrict__ xm,
                                                         const float* __restrict__ xa,
                                                         const int* __restrict__ idx,
                                                         float* __restrict__ vmainT,
                                                         float* __restrict__ vauxT) {
  extern __shared__ float plane2[];  // 2 * HW floats = 128 KB
  int g = blockIdx.x, b = blockIdx.y, z = blockIdx.z;
  int tid = threadIdx.x;
  int c0 = g * CPG;
  const float* src = (z == 0 ? xm : xa) + ((size_t)(b * CCH + c0)) * HW;
  float* dst = (z == 0 ? vmainT : vauxT) + (((size_t)(b * CCH + c0)) << 9);

  // per-point patch geometry, once per block (same point set for all channels)
  int t500 = (tid < NSEL) ? tid : 0;
  int p = idx[b * NPAD + t500];
  float wx[7], wy[7];
  int xc[7], yc[7], rb[7];
  patch_weights(p, xc, yc, wx, wy);
#pragma unroll
  for (int d = 0; d < 7; d++) rb[d] = yc[d] * WID;

  // prologue: DMA plane 0 into buffer 0
#pragma unroll
  for (int j = 0; j < 8; j++) {
    int off = (tid + j * 512) * 4;
    __builtin_amdgcn_global_load_lds(
        (const __attribute__((address_space(1))) float*)(src + off),
        (__attribute__((address_space(3))) float*)(plane2 + off), 16, 0, 0);
  }
  __syncthreads();  // drains vmcnt(0): plane 0 resident

  for (int c = 0; c < CPG; c++) {
    float* cur = plane2 + ((c & 1) ? HW : 0);
    float* nxt = plane2 + ((c & 1) ? 0 : HW);
    if (c + 1 < CPG) {
      const float* s2 = src + (size_t)(c + 1) * HW;
#pragma unroll
      for (int j = 0; j < 8; j++) {
        int off = (tid + j * 512) * 4;
        __builtin_amdgcn_global_load_lds(
            (const __attribute__((address_space(1))) float*)(s2 + off),
            (__attribute__((address_space(3))) float*)(nxt + off), 16, 0, 0);
      }
    }
    if (tid < NSEL) {
      float s = 0.f, mx = -INFINITY;
#pragma unroll
      for (int dy = 0; dy < 7; dy++) {
        float rs = 0.f, rm = -INFINITY;
        int rbb = rb[dy];
        float wyd = wy[dy];
#pragma unroll
        for (int dx = 0; dx < 7; dx++) {
          float v = cur[rbb + xc[dx]] * wx[dx];
          rs += v;
          rm = fmaxf(rm, v);
        }
        s += rs * wyd;
        mx = fmaxf(mx, rm * wyd);
      }
      dst[((size_t)c << 9) + tid] = 0.5f * (s * (1.f / 49.f) + mx);
    } else {
      dst[((size_t)c << 9) + tid] = 0.f;  // zero pad rows: no 0*garbage downstream
    }
    __syncthreads();  // all waves done with cur; nxt DMA drained (vmcnt(0))
  }
}

// ---------- tiled fp32 GEMM (used for sim only): C[b] = A[b]^T(KxM) * B(KxN), *0.0625 ----------
template <int M, int N, int K>
__global__ __launch_bounds__(256) void gemm_tn_kernel(const float* __restrict__ A,
                                                      const float* __restrict__ B,
                                                      float* __restrict__ C) {
  constexpr int BM = 64, BN = 64, BK = 16;
  __shared__ float As[BK][BM + 4];
  __shared__ float Bs[BK][BN + 4];
  int tid = threadIdx.x;
  int bx = blockIdx.x, by = blockIdx.y, b = blockIdx.z;
  const float* Ab = A + (size_t)b * M * K;
  const float* Bb = B + (size_t)b * ((size_t)K * N);
  int tx = tid & 15, ty = tid >> 4;
  float acc[4][4] = {};
  int kr = tid >> 4, mc = (tid & 15) * 4;   // A K-major staging
  int br = tid >> 4, bc4 = (tid & 15) * 4;  // B row-major staging

  float4 avr = *(const float4*)&Ab[(size_t)kr * M + by * BM + mc];
  float4 bvr = *(const float4*)&Bb[(size_t)br * N + bx * BN + bc4];
  for (int k0 = 0; k0 < K; k0 += BK) {
    *(float4*)&As[kr][mc] = avr;
    *(float4*)&Bs[br][bc4] = bvr;
    __syncthreads();
    if (k0 + BK < K) {
      avr = *(const float4*)&Ab[(size_t)(k0 + BK + kr) * M + by * BM + mc];
      bvr = *(const float4*)&Bb[(size_t)(k0 + BK + br) * N + bx * BN + bc4];
    }
#pragma unroll
    for (int kk = 0; kk < BK; kk++) {
      const float4 a = *(const float4*)&As[kk][ty * 4];
      const float4 bb = *(const float4*)&Bs[kk][tx * 4];
      float av[4] = {a.x, a.y, a.z, a.w};
      float bv[4] = {bb.x, bb.y, bb.z, bb.w};
#pragma unroll
      for (int rr = 0; rr < 4; rr++)
#pragma unroll
        for (int ss = 0; ss < 4; ss++) acc[rr][ss] += av[rr] * bv[ss];
    }
    __syncthreads();
  }
#pragma unroll
  for (int r = 0; r < 4; r++) {
    int row = by * BM + ty * 4 + r;
#pragma unroll
    for (int s = 0; s < 4; s++) {
      int col = bx * BN + tx * 4 + s;
      C[((size_t)b * M + row) * N + col] = acc[r][s] * 0.0625f;  // 1/sqrt(256)
    }
  }
}

// ---------- fused softmax + GEMM2: vhat[b][i][c] = softmax_j(sim[b][i][:500]) @ vauxT[b][c][:]^T ----
// Each block's A-tile spans the FULL sim row (K=512), so row stats (max, sum of exp
// over j<500) are computed in a cheap L2-hot pre-pass; P is materialized on the fly
// while staging As. Removes the softmax kernel + its global round-trip.
__global__ __launch_bounds__(256) void attn_gemm_kernel(const float* __restrict__ sim,
                                                        const float* __restrict__ vaux,
                                                        float* __restrict__ vhat) {
  constexpr int BM = 64, BN = 64, BK = 16;
  __shared__ float As[BK][BM + 4];
  __shared__ float Bs[BK][BN + 4];
  __shared__ float red[BM][4];
  __shared__ float sm_m[BM], sm_inv[BM];
  int tid = threadIdx.x;
  int bx = blockIdx.x, by = blockIdx.y, b = blockIdx.z;
  const float* Ab = sim + ((size_t)b * NPAD + by * BM) * NPAD;
  const float* Bb = vaux + (size_t)b * CCH * NPAD;

  // ---- phase A: per-row max & expsum over j<NSEL (4 threads per row) ----
  int rr = tid >> 2, q = tid & 3;
  int j0 = q * 128, j1 = (j0 + 128 < NSEL) ? j0 + 128 : NSEL;  // 128,256,384,500
  const float* rowp = Ab + (size_t)rr * NPAD;
  float m = -INFINITY;
  for (int j = j0; j < j1; j += 4) {
    float4 v = *(const float4*)&rowp[j];
    m = fmaxf(fmaxf(fmaxf(m, v.x), v.y), fmaxf(v.z, v.w));
  }
  red[rr][q] = m;
  __syncthreads();
  m = fmaxf(fmaxf(red[rr][0], red[rr][1]), fmaxf(red[rr][2], red[rr][3]));
  float s = 0.f;
  for (int j = j0; j < j1; j += 4) {
    float4 v = *(const float4*)&rowp[j];
    s += expf(v.x - m) + expf(v.y - m) + expf(v.z - m) + expf(v.w - m);
  }
  __syncthreads();
  red[rr][q] = s;
  __syncthreads();
  if (q == 0) {
    sm_m[rr] = m;
    sm_inv[rr] = 1.f / (red[rr][0] + red[rr][1] + red[rr][2] + red[rr][3]);
  }
  __syncthreads();

  // ---- phase B: GEMM with on-the-fly P = exp(v-m)*inv (masked j>=NSEL) ----
  int tx = tid & 15, ty = tid >> 4;
  float acc[4][4] = {};
  int ar = tid >> 2, ac4 = (tid & 3) * 4;  // As staging: A row-major, k-major LDS scatter
  int nr = tid >> 2, kc4 = (tid & 3) * 4;  // Bs staging: B is N-major (c rows) x K(j)
  float mr = sm_m[ar], ir = sm_inv[ar];

  float4 avr = *(const float4*)&Ab[(size_t)ar * NPAD + ac4];
  float4 bvr = *(const float4*)&Bb[(size_t)(bx * BN + nr) * NPAD + kc4];
  for (int k0 = 0; k0 < NPAD; k0 += BK) {
    int kb = k0 + ac4;
    As[ac4 + 0][ar] = (kb + 0 < NSEL) ? expf(avr.x - mr) * ir : 0.f;
    As[ac4 + 1][ar] = (kb + 1 < NSEL) ? expf(avr.y - mr) * ir : 0.f;
    As[ac4 + 2][ar] = (kb + 2 < NSEL) ? expf(avr.z - mr) * ir : 0.f;
    As[ac4 + 3][ar] = (kb + 3 < NSEL) ? expf(avr.w - mr) * ir : 0.f;
    Bs[kc4 + 0][nr] = bvr.x; Bs[kc4 + 1][nr] = bvr.y;
    Bs[kc4 + 2][nr] = bvr.z; Bs[kc4 + 3][nr] = bvr.w;
    __syncthreads();
    if (k0 + BK < NPAD) {
      avr = *(const float4*)&Ab[(size_t)ar * NPAD + k0 + BK + ac4];
      bvr = *(const float4*)&Bb[(size_t)(bx * BN + nr) * NPAD + k0 + BK + kc4];
    }
#pragma unroll
    for (int kk = 0; kk < BK; kk++) {
      const float4 a = *(const float4*)&As[kk][ty * 4];
      const float4 bb = *(const float4*)&Bs[kk][tx * 4];
      float av[4] = {a.x, a.y, a.z, a.w};
      float bv[4] = {bb.x, bb.y, bb.z, bb.w};
#pragma unroll
      for (int r2 = 0; r2 < 4; r2++)
#pragma unroll
        for (int s2 = 0; s2 < 4; s2++) acc[r2][s2] += av[r2] * bv[s2];
    }
    __syncthreads();
  }
#pragma unroll
  for (int r = 0; r < 4; r++) {
    int row = by * BM + ty * 4 + r;
#pragma unroll
    for (int s2 = 0; s2 < 4; s2++) {
      int col = bx * BN + tx * 4 + s2;
      vhat[((size_t)b * NPAD + row) * CCH + col] = acc[r][s2];
    }
  }
}

// ---------- gated-fusion MLP: vfused = vm + gate*(vm - vhat) ----------
__global__ __launch_bounds__(256) void mlp_kernel(const float* __restrict__ vmainT,
                                                  const float* __restrict__ vhat,
                                                  const float* __restrict__ fc1w,
                                                  const float* __restrict__ fc1b,
                                                  const float* __restrict__ fc2w,
                                                  const float* __restrict__ fc2b,
                                                  float* __restrict__ vfused) {
  int i = blockIdx.x, b = blockIdx.y, c = threadIdx.x;
  size_t base = ((size_t)b * NPAD + i) * CCH + c;
  float vm = vmainT[(((size_t)(b * CCH + c)) << 9) + i];
  float vh = vhat[base], vd = vm - vh;
  const float* w0 = fc1w + (size_t)c * 16;
  const float* w1 = fc1w + (size_t)(256 + c) * 16;
  const float* w2 = fc1w + (size_t)(512 + c) * 16;
  __shared__ float ph[256][17];    // [c][k], +1 pad: conflict-free both axes
  __shared__ float part2[16][17];  // [group][k]
  __shared__ float hsh[16];
#pragma unroll
  for (int k = 0; k < 16; k++) ph[c][k] = vm * w0[k] + vh * w1[k] + vd * w2[k];
  __syncthreads();
  int kk = c & 15, g = c >> 4;
  float part = 0.f;
#pragma unroll
  for (int j = 0; j < 16; j++) part += ph[g * 16 + j][kk];
  part2[g][kk] = part;
  __syncthreads();
  if (c < 16) {
    float s = fc1b[c];
#pragma unroll
    for (int g2 = 0; g2 < 16; g2++) s += part2[g2][c];
    hsh[c] = fmaxf(s, 0.f);
  }
  __syncthreads();
  float gte = fc2b[c];
#pragma unroll
  for (int k = 0; k < 16; k++) gte += hsh[k] * fc2w[k * 256 + c];
  gte = 1.f / (1.f + expf(-gte));
  vfused[base] = vm + gte * vd;
}

// ---------- fused proj GEMM + sparse scatter into out ----------
// C_inj[b][col][row] = (vfused @ proj_w + proj_b); directly RMW
// out[b][col][ pix[row] ] += C_inj. Each (b,col,pix) is unique -> no atomics.
// Removes the vinjT buffer round-trip and the standalone scatter kernel.
__global__ __launch_bounds__(256) void proj_scatter_kernel(const float* __restrict__ vfused,
                                                           const float* __restrict__ Bw,
                                                           const float* __restrict__ bias,
                                                           const int* __restrict__ idx,
                                                           float* __restrict__ out) {
  constexpr int BM = 64, BN = 64, BK = 16;
  __shared__ float As[BK][BM + 4];
  __shared__ float Bs[BK][BN + 4];
  __shared__ int pix[BM];
  int tid = threadIdx.x;
  int bx = blockIdx.x, by = blockIdx.y, b = blockIdx.z;
  if (tid < BM) {
    int row = by * BM + tid;
    pix[tid] = (row < NSEL) ? idx[b * NPAD + row] : -1;
  }
  const float* Ab = vfused + (size_t)b * NPAD * CCH;
  int tx = tid & 15, ty = tid >> 4;
  float acc[4][4] = {};
  int ar = tid >> 2, ac4 = (tid & 3) * 4;   // A row-major staging
  int br = tid >> 4, bc4 = (tid & 15) * 4;  // B row-major staging

  float4 avr = *(const float4*)&Ab[(size_t)(by * BM + ar) * CCH + ac4];
  float4 bvr = *(const float4*)&Bw[(size_t)br * CCH + bx * BN + bc4];
  for (int k0 = 0; k0 < CCH; k0 += BK) {
    As[ac4 + 0][ar] = avr.x; As[ac4 + 1][ar] = avr.y;
    As[ac4 + 2][ar] = avr.z; As[ac4 + 3][ar] = avr.w;
    *(float4*)&Bs[br][bc4] = bvr;
    __syncthreads();
    if (k0 + BK < CCH) {
      avr = *(const float4*)&Ab[(size_t)(by * BM + ar) * CCH + k0 + BK + ac4];
      bvr = *(const float4*)&Bw[(size_t)(k0 + BK + br) * CCH + bx * BN + bc4];
    }
#pragma unroll
    for (int kk = 0; kk < BK; kk++) {
      const float4 a = *(const float4*)&As[kk][ty * 4];
      const float4 bb = *(const float4*)&Bs[kk][tx * 4];
      float av[4] = {a.x, a.y, a.z, a.w};
      float bv[4] = {bb.x, bb.y, bb.z, bb.w};
#pragma unroll
      for (int rr = 0; rr < 4; rr++)
#pragma unroll
        for (int ss = 0; ss < 4; ss++) acc[rr][ss] += av[rr] * bv[ss];
    }
    __syncthreads();
  }
#pragma unroll
  for (int r = 0; r < 4; r++) {
    int p = pix[ty * 4 + r];
    if (p >= 0) {
#pragma unroll
      for (int s = 0; s < 4; s++) {
        int col = bx * BN + tx * 4 + s;
        float* o = out + (((size_t)(b * CCH + col)) << 14) + p;
        *o += acc[r][s] + bias[col];
      }
    }
  }
}

extern "C" void kernel_launch(void* const* d_in, const int* in_sizes, int n_in,
                              void* d_out, int out_size, void* d_ws, size_t ws_size,
                              hipStream_t stream) {
  const float* x_main   = (const float*)d_in[0];
  const float* x_aux    = (const float*)d_in[1];
  const float* scorer_w = (const float*)d_in[2];
  // d_in[3] scorer_b: constant shift, irrelevant to top-k set -> unused
  const float* fc1_w = (const float*)d_in[4];
  const float* fc1_b = (const float*)d_in[5];
  const float* fc2_w = (const float*)d_in[6];
  const float* fc2_b = (const float*)d_in[7];
  const float* proj_w = (const float*)d_in[8];
  const float* proj_b = (const float*)d_in[9];
  // d_in[10] n == 500 (fixed)
  (void)in_sizes; (void)n_in; (void)out_size; (void)ws_size;

  float* ws = (float*)d_ws;
  // workspace layout (floats), ~26 MB total
  float* logits = ws;                      // 131072
  int*   idx    = (int*)(ws + 131072);     // 4096
  float* vmainT = ws + 266240;             // 1048576  [b][c][i]
  float* vauxT  = ws + 1314816;            // 1048576  [b][c][j]
  float* vhat   = ws + 2363392;            // 1048576  [b][i][c]
  float* vfused = ws + 3411968;            // 1048576  [b][i][c]
  float* sim    = ws + 4460544;            // 2097152  [b][i][j]
  float* out = (float*)d_out;

  score_copy_kernel<<<512, 256, 0, stream>>>(x_main, scorer_w, logits, out);
  topk_kernel<<<NB, 1024, 0, stream>>>(logits, idx);
  gather_dma_kernel<<<dim3(CCH / CPG, NB, 2), 512, 2 * HW * sizeof(float), stream>>>(
      x_main, x_aux, idx, vmainT, vauxT);
  // sim[b][i][j] = sum_c vmainT[b][c][i] * vauxT[b][c][j] / 16   (TN gemm)
  gemm_tn_kernel<NPAD, NPAD, CCH>
      <<<dim3(8, 8, NB), 256, 0, stream>>>(vmainT, vauxT, sim);
  // fused: softmax_j(sim) @ vauxT^T -> vhat[b][i][c]
  attn_gemm_kernel<<<dim3(4, 8, NB), 256, 0, stream>>>(sim, vauxT, vhat);
  mlp_kernel<<<dim3(NPAD, NB), 256, 0, stream>>>(vmainT, vhat, fc1_w, fc1_b,
                                                 fc2_w, fc2_b, vfused);
  // fused: (vfused @ proj_w + proj_b) scattered into out at the topk pixels
  proj_scatter_kernel<<<dim3(4, 8, NB), 256, 0, stream>>>(vfused, proj_w, proj_b,
                                                          idx, out);
}